// Round 10
// baseline (148.534 us; speedup 1.0000x reference)
//
#include <hip/hip_runtime.h>

#define NN 50000
#define EE 1600000
#define CC 128
#define HH 8
#define TOT (EE + NN)               // 1,650,000 output rows
#define RPB 64                      // rows per bucket
#define NB  ((NN + RPB - 1) / RPB)  // 782 buckets
#define BCH 4096                    // edges per binning block
#define NBB ((EE + BCH - 1) / BCH)  // 391 binning blocks
#define SCAP 3584                   // sort stage capacity (mean 2048)
#define NIT 8                       // cached iterations (tot<=64 typical)

typedef unsigned long long ull;

// leaky_relu(z,0.2)*100
__device__ inline float act(float z) {
    z = (z >= 0.f) ? z : 0.2f * z;
    return z * 100.f;
}

// ---- yk[r] = [x@W1 + b (8) | K placeholder (8)], y2 = x @ W[C:] ----
// block 0 additionally zero-inits gcnt/gcur0 and writes rstart[NN]=EE
__global__ __launch_bounds__(256) void k_proj(const float* __restrict__ x,
                                              const float* __restrict__ W,
                                              const float* __restrict__ bias,
                                              float* __restrict__ yk,
                                              float* __restrict__ y2,
                                              int* __restrict__ gcnt,
                                              int* __restrict__ gcur0,
                                              int* __restrict__ rstart) {
    if (blockIdx.x == 0) {
        for (int i = threadIdx.x; i < NB; i += 256) { gcnt[i] = 0; gcur0[i] = 0; }
        if (threadIdx.x == 0) rstart[NN] = EE;
    }
    __shared__ float w[2 * CC * HH];  // 2048 floats
    int tid = threadIdx.x;
    for (int i = tid; i < 2 * CC * HH; i += 256) w[i] = W[i];
    __syncthreads();
    int node = blockIdx.x * 16 + (tid >> 4);
    int j = tid & 15;
    if (node >= NN) return;
    int wofs = (j < 8) ? j : (CC * HH + j - 8);
    const float4* xv = (const float4*)(x + (size_t)node * CC);
    float acc = 0.f;
#pragma unroll 4
    for (int k4 = 0; k4 < CC / 4; ++k4) {
        float4 xx = xv[k4];
        int base = k4 * 32 + wofs;
        acc += xx.x * w[base];
        acc += xx.y * w[base + 8];
        acc += xx.z * w[base + 16];
        acc += xx.w * w[base + 24];
    }
    if (j < 8) yk[(size_t)node * 16 + j] = acc + bias[j];
    else       y2[(size_t)node * 8 + (j - 8)] = acc;
}

// ---- bucket histogram: LDS-aggregated ----
__global__ __launch_bounds__(1024) void k_hist(const int* __restrict__ rowp,
                                               int* __restrict__ gcnt) {
    __shared__ int h[NB];
    int t = threadIdx.x;
    for (int i = t; i < NB; i += 1024) h[i] = 0;
    __syncthreads();
    int base = blockIdx.x * BCH;
    int n = EE - base; if (n > BCH) n = BCH;
    for (int i = t; i < n; i += 1024) {
        int r = __builtin_nontemporal_load(&rowp[base + i]);
        atomicAdd(&h[r >> 6], 1);
    }
    __syncthreads();
    for (int i = t; i < NB; i += 1024)
        if (h[i]) atomicAdd(&gcnt[i], h[i]);
}

// ---- binning: computes global bucket bases itself; packs payload;
//      LDS stage + per-bucket coalesced chunk flush ----
__global__ __launch_bounds__(1024) void k_bin(const int* __restrict__ rowp,
                                              const int* __restrict__ colp,
                                              const float* __restrict__ ea,
                                              const int* __restrict__ gcnt,
                                              int* __restrict__ gcur0,
                                              uint2* __restrict__ pay) {
    __shared__ int hist[NB];
    __shared__ int lscan[NB];
    __shared__ int lofs[NB];
    __shared__ int gofs[NB];
    __shared__ int sc[1024];
    __shared__ uint2 stage[BCH];   // 32 KB
    int t = threadIdx.x;
    int base = blockIdx.x * BCH;
    int n = EE - base; if (n > BCH) n = BCH;
    for (int i = t; i < NB; i += 1024) hist[i] = 0;
    __syncthreads();
    for (int i = t; i < n; i += 1024) {
        int r = __builtin_nontemporal_load(&rowp[base + i]);
        atomicAdd(&hist[r >> 6], 1);
    }
    __syncthreads();
    // scan 1: global gcnt -> exclusive bucket base gb (per thread t==bucket)
    int og = (t < NB) ? gcnt[t] : 0;
    sc[t] = og;
    __syncthreads();
    for (int off = 1; off < 1024; off <<= 1) {
        int v = (t >= off) ? sc[t - off] : 0;
        __syncthreads();
        sc[t] += v;
        __syncthreads();
    }
    int gb = sc[t] - og;
    __syncthreads();
    // scan 2: local chunk hist -> stage layout
    int own = (t < NB) ? hist[t] : 0;
    sc[t] = own;
    __syncthreads();
    for (int off = 1; off < 1024; off <<= 1) {
        int v = (t >= off) ? sc[t - off] : 0;
        __syncthreads();
        sc[t] += v;
        __syncthreads();
    }
    if (t < NB) {
        int ex = sc[t] - own;
        lscan[t] = ex;
        lofs[t] = ex;
        gofs[t] = own ? (gb + atomicAdd(&gcur0[t], own)) : 0;
    }
    __syncthreads();
    // place packed payload into stage, grouped by bucket
    for (int i = t; i < n; i += 1024) {
        int r = __builtin_nontemporal_load(&rowp[base + i]);
        int c = __builtin_nontemporal_load(&colp[base + i]);
        float w = fabsf(__builtin_nontemporal_load(&ea[base + i]));
        int bkt = r >> 6;
        int p = atomicAdd(&lofs[bkt], 1);
        stage[p] = make_uint2((unsigned)(r & 63) | ((unsigned)c << 6) |
                              ((unsigned)bkt << 22),
                              __float_as_uint(w));
    }
    __syncthreads();
    // flush: consecutive staged slots of a bucket -> consecutive global slots
    for (int i = t; i < n; i += 1024) {
        uint2 v = stage[i];
        int bkt = v.x >> 22;
        pay[gofs[bkt] + (i - lscan[bkt])] = v;
    }
}

// ---- per-bucket counting sort by rloc -> row-sorted pay2=(c,w), rstart ----
__global__ __launch_bounds__(256) void k_sort(const int* __restrict__ gcnt,
                                              const uint2* __restrict__ pay,
                                              uint2* __restrict__ pay2,
                                              int* __restrict__ rstart) {
    __shared__ int cnt[RPB];
    __shared__ int ofs2[RPB];
    __shared__ int red[256];
    __shared__ uint2 stg[SCAP];   // 28 KB
    int b = blockIdx.x;
    int t = threadIdx.x;
    // s0 = sum_{i<b} gcnt[i]
    int part = 0;
    for (int i = t; i < b; i += 256) part += gcnt[i];
    red[t] = part;
    __syncthreads();
    for (int off = 128; off > 0; off >>= 1) {
        if (t < off) red[t] += red[t + off];
        __syncthreads();
    }
    int s0 = red[0];
    int n = gcnt[b];
    if (t < RPB) cnt[t] = 0;
    __syncthreads();
    for (int i = t; i < n; i += 256) {
        ull pv = __builtin_nontemporal_load((const ull*)(pay + s0 + i));
        atomicAdd(&cnt[(unsigned)pv & 63], 1);
    }
    __syncthreads();
    if (t < RPB) {
        int v = cnt[t];
        int s = v;
        for (int off = 1; off < 64; off <<= 1) {
            int u = __shfl_up(s, off, 64);
            if (t >= off) s += u;
        }
        int ex = s - v;               // exclusive
        ofs2[t] = ex;
        int r0 = b * RPB;
        int nrows = NN - r0; if (nrows > RPB) nrows = RPB;
        if (t < nrows) rstart[r0 + t] = s0 + ex;
    }
    __syncthreads();
    for (int i = t; i < n; i += 256) {
        ull pv = __builtin_nontemporal_load((const ull*)(pay + s0 + i));
        unsigned px = (unsigned)pv;
        int rl = px & 63;
        int pos = atomicAdd(&ofs2[rl], 1);
        stg[pos] = make_uint2((px >> 6) & 0xFFFF, (unsigned)(pv >> 32));
    }
    __syncthreads();
    for (int i = t; i < n; i += 256)
        pay2[s0 + i] = stg[i];
}

// ---- row-parallel softmax stats: one wave per row -> K = m + log(s+eps) ----
__global__ __launch_bounds__(256) void k_row(const int* __restrict__ rstart,
                                             const uint2* __restrict__ pay2,
                                             float* __restrict__ yk,
                                             const float* __restrict__ y2) {
    int wv = threadIdx.x >> 6;
    int lane = threadIdx.x & 63;
    int r = blockIdx.x * 4 + wv;
    if (r >= NN) return;
    int sub = lane >> 3;   // edge slot within chunk (0..7)
    int h = lane & 7;      // head
    int s0 = rstart[r];
    int deg = rstart[r + 1] - s0;
    int tot = deg + 1;     // + self loop at slot == deg
    float yh = yk[(size_t)r * 16 + h];
    float y2s = y2[(size_t)r * 8 + h];
    float cache[NIT];
    float mx = -__builtin_inff();
#pragma unroll
    for (int it = 0; it < NIT; ++it) {
        int i = it * 8 + sub;
        float a = -__builtin_inff();
        if (i < deg) {
            ull pv = __builtin_nontemporal_load((const ull*)(pay2 + s0 + i));
            unsigned c = (unsigned)pv;
            float w = __uint_as_float((unsigned)(pv >> 32));
            a = act((yh + y2[(size_t)c * 8 + h]) * w);
        } else if (i == deg) {
            a = act(yh + y2s);
        }
        cache[it] = a;
        mx = fmaxf(mx, a);
    }
    for (int i = NIT * 8 + sub; i < tot; i += 8) {
        float a;
        if (i < deg) {
            ull pv = __builtin_nontemporal_load((const ull*)(pay2 + s0 + i));
            unsigned c = (unsigned)pv;
            float w = __uint_as_float((unsigned)(pv >> 32));
            a = act((yh + y2[(size_t)c * 8 + h]) * w);
        } else {
            a = act(yh + y2s);
        }
        mx = fmaxf(mx, a);
    }
    mx = fmaxf(mx, __shfl_xor(mx, 8, 64));
    mx = fmaxf(mx, __shfl_xor(mx, 16, 64));
    mx = fmaxf(mx, __shfl_xor(mx, 32, 64));
    float sum = 0.f;
#pragma unroll
    for (int it = 0; it < NIT; ++it)
        sum += __expf(cache[it] - mx);   // exp(-inf) = 0 for empty slots
    for (int i = NIT * 8 + sub; i < tot; i += 8) {
        float a;
        if (i < deg) {
            ull pv = __builtin_nontemporal_load((const ull*)(pay2 + s0 + i));
            unsigned c = (unsigned)pv;
            float w = __uint_as_float((unsigned)(pv >> 32));
            a = act((yh + y2[(size_t)c * 8 + h]) * w);
        } else {
            a = act(yh + y2s);
        }
        sum += __expf(a - mx);
    }
    sum += __shfl_xor(sum, 8, 64);
    sum += __shfl_xor(sum, 16, 64);
    sum += __shfl_xor(sum, 32, 64);
    if (sub == 0)
        yk[(size_t)r * 16 + 8 + h] = mx + __logf(sum + 1e-16f);
}

// ---- finalize: 8 lanes per output row; 2 gather-lines per edge ----
__global__ __launch_bounds__(256) void k_final(const int* __restrict__ rowp,
                                               const int* __restrict__ colp,
                                               const float* __restrict__ ea,
                                               const float* __restrict__ yk,
                                               const float* __restrict__ y2,
                                               float* __restrict__ alpha,
                                               float* __restrict__ oidx) {
    long long g = (long long)blockIdx.x * 256 + threadIdx.x;
    int e = (int)(g >> 3);
    int h = (int)(g & 7);
    if (e >= TOT) return;
    int r, c; float w;
    if (e < EE) {
        r = __builtin_nontemporal_load(&rowp[e]);
        c = __builtin_nontemporal_load(&colp[e]);
        w = fabsf(__builtin_nontemporal_load(&ea[e]));
    } else {
        r = e - EE; c = r; w = 1.0f;
    }
    float yv = yk[(size_t)r * 16 + h];
    float Kv = yk[(size_t)r * 16 + 8 + h];
    float vb = y2[(size_t)c * 8 + h];
    float a = act((yv + vb) * w);
    float o = __expf(a - Kv);
    __builtin_nontemporal_store(o, &alpha[(size_t)e * 8 + h]);
    if (h == 0) __builtin_nontemporal_store((float)r, &oidx[e]);
    if (h == 1) __builtin_nontemporal_store((float)c, &oidx[(size_t)TOT + e]);
}

extern "C" void kernel_launch(void* const* d_in, const int* in_sizes, int n_in,
                              void* d_out, int out_size, void* d_ws, size_t ws_size,
                              hipStream_t stream) {
    const float* x    = (const float*)d_in[0];
    const int*   rowp = (const int*)d_in[1];          // edge_index[0]
    const int*   colp = rowp + EE;                    // edge_index[1]
    const float* ea   = (const float*)d_in[2];
    const float* W    = (const float*)d_in[3];
    const float* bias = (const float*)d_in[4];

    float* out_alpha = (float*)d_out;                 // [TOT][8]
    float* out_idx   = out_alpha + (size_t)TOT * 8;   // [2][TOT] as float

    // pay2 (row-sorted payload, EE uint2 = 12.8MB) lives in the out_alpha
    // region: fully consumed by k_row before k_final overwrites it.
    uint2* pay2 = (uint2*)out_alpha;

    // workspace layout
    float*  yk     = (float*)d_ws;                    // NN*16 (y1b | K), 64B/row
    float*  y2     = yk + (size_t)NN * 16;            // NN*8
    uint2*  pay    = (uint2*)(y2 + (size_t)NN * 8);   // EE uint2 (12.8 MB)
    int*    gcnt   = (int*)(pay + (size_t)EE);        // NB
    int*    gcur0  = gcnt + NB;                       // NB (zeroed by k_proj)
    int*    rstart = gcur0 + NB;                      // NN+1

    k_proj<<<(NN * 16 + 255) / 256, 256, 0, stream>>>(x, W, bias, yk, y2,
                                                      gcnt, gcur0, rstart);
    k_hist<<<NBB, 1024, 0, stream>>>(rowp, gcnt);
    k_bin<<<NBB, 1024, 0, stream>>>(rowp, colp, ea, gcnt, gcur0, pay);
    k_sort<<<NB, 256, 0, stream>>>(gcnt, pay, pay2, rstart);
    k_row<<<(NN + 3) / 4, 256, 0, stream>>>(rstart, pay2, yk, y2);
    long long fin_threads = (long long)TOT * 8;
    int fin_blocks = (int)((fin_threads + 255) / 256);
    k_final<<<fin_blocks, 256, 0, stream>>>(rowp, colp, ea, yk, y2,
                                            out_alpha, out_idx);
}

// Round 11
// 140.246 us; speedup vs baseline: 1.0591x; 1.0591x over previous
//
#include <hip/hip_runtime.h>

#define NN 50000
#define EE 1600000
#define CC 128
#define HH 8
#define TOT (EE + NN)               // 1,650,000 output rows
#define RPB 64                      // rows per bucket
#define NB  ((NN + RPB - 1) / RPB)  // 782 buckets
#define BCH 4096                    // edges per binning block
#define NBB ((EE + BCH - 1) / BCH)  // 391 binning blocks
#define SCAP 3584                   // sort stage capacity (mean 2048)
#define NIT 8                       // cached iterations (tot<=64 typical)
#define GRIDF 4096                  // k_final grid-stride blocks

typedef unsigned long long ull;

// leaky_relu(z,0.2)*100
__device__ inline float act(float z) {
    z = (z >= 0.f) ? z : 0.2f * z;
    return z * 100.f;
}

// ---- yk[r] = [x@W1 + b (8) | K placeholder (8)], y2 = x @ W[C:] ----
// block 0 additionally zero-inits gcnt/gcur0
__global__ __launch_bounds__(256) void k_proj(const float* __restrict__ x,
                                              const float* __restrict__ W,
                                              const float* __restrict__ bias,
                                              float* __restrict__ yk,
                                              float* __restrict__ y2,
                                              int* __restrict__ gcnt,
                                              int* __restrict__ gcur0,
                                              int* __restrict__ rstart) {
    if (blockIdx.x == 0) {
        for (int i = threadIdx.x; i < NB; i += 256) { gcnt[i] = 0; gcur0[i] = 0; }
        if (threadIdx.x == 0) rstart[NN] = EE;
    }
    __shared__ float w[2 * CC * HH];  // 2048 floats
    int tid = threadIdx.x;
    for (int i = tid; i < 2 * CC * HH; i += 256) w[i] = W[i];
    __syncthreads();
    int node = blockIdx.x * 16 + (tid >> 4);
    int j = tid & 15;
    if (node >= NN) return;
    int wofs = (j < 8) ? j : (CC * HH + j - 8);
    const float4* xv = (const float4*)(x + (size_t)node * CC);
    float acc = 0.f;
#pragma unroll 4
    for (int k4 = 0; k4 < CC / 4; ++k4) {
        float4 xx = xv[k4];
        int base = k4 * 32 + wofs;
        acc += xx.x * w[base];
        acc += xx.y * w[base + 8];
        acc += xx.z * w[base + 16];
        acc += xx.w * w[base + 24];
    }
    if (j < 8) yk[(size_t)node * 16 + j] = acc + bias[j];
    else       y2[(size_t)node * 8 + (j - 8)] = acc;
}

// ---- bucket histogram: LDS-aggregated ----
__global__ __launch_bounds__(1024) void k_hist(const int* __restrict__ rowp,
                                               int* __restrict__ gcnt) {
    __shared__ int h[NB];
    int t = threadIdx.x;
    for (int i = t; i < NB; i += 1024) h[i] = 0;
    __syncthreads();
    int base = blockIdx.x * BCH;
    int n = EE - base; if (n > BCH) n = BCH;
    for (int i = t; i < n; i += 1024)
        atomicAdd(&h[rowp[base + i] >> 6], 1);
    __syncthreads();
    for (int i = t; i < NB; i += 1024)
        if (h[i]) atomicAdd(&gcnt[i], h[i]);
}

// ---- binning: fused global+local scan (packed u64); LDS stage; coalesced flush
__global__ __launch_bounds__(1024) void k_bin(const int* __restrict__ rowp,
                                              const int* __restrict__ colp,
                                              const float* __restrict__ ea,
                                              const int* __restrict__ gcnt,
                                              int* __restrict__ gcur0,
                                              uint2* __restrict__ pay) {
    __shared__ int hist[NB];
    __shared__ int lscan[NB];
    __shared__ int lofs[NB];
    __shared__ int gofs[NB];
    __shared__ ull sc[1024];
    __shared__ uint2 stage[BCH];   // 32 KB
    int t = threadIdx.x;
    int base = blockIdx.x * BCH;
    int n = EE - base; if (n > BCH) n = BCH;
    for (int i = t; i < NB; i += 1024) hist[i] = 0;
    __syncthreads();
    for (int i = t; i < n; i += 1024)
        atomicAdd(&hist[rowp[base + i] >> 6], 1);
    __syncthreads();
    // packed scan: high 32 = global gcnt, low 32 = local hist
    int og  = (t < NB) ? gcnt[t] : 0;
    int own = (t < NB) ? hist[t] : 0;
    sc[t] = ((ull)(unsigned)og << 32) | (unsigned)own;
    __syncthreads();
    for (int off = 1; off < 1024; off <<= 1) {
        ull v = (t >= off) ? sc[t - off] : 0ull;
        __syncthreads();
        sc[t] += v;
        __syncthreads();
    }
    if (t < NB) {
        int gb = (int)(sc[t] >> 32) - og;             // global bucket base
        int ex = (int)(sc[t] & 0xFFFFFFFFu) - own;    // local stage base
        lscan[t] = ex;
        lofs[t] = ex;
        gofs[t] = own ? (gb + atomicAdd(&gcur0[t], own)) : 0;
    }
    __syncthreads();
    // place packed payload into stage, grouped by bucket
    for (int i = t; i < n; i += 1024) {
        int r = rowp[base + i];
        int c = colp[base + i];
        float w = fabsf(ea[base + i]);
        int bkt = r >> 6;
        int p = atomicAdd(&lofs[bkt], 1);
        stage[p] = make_uint2((unsigned)(r & 63) | ((unsigned)c << 6) |
                              ((unsigned)bkt << 22),
                              __float_as_uint(w));
    }
    __syncthreads();
    // flush: consecutive staged slots of a bucket -> consecutive global slots
    for (int i = t; i < n; i += 1024) {
        uint2 v = stage[i];
        int bkt = v.x >> 22;
        pay[gofs[bkt] + (i - lscan[bkt])] = v;
    }
}

// ---- per-bucket counting sort by rloc -> row-sorted pay2=(c,w), rstart ----
__global__ __launch_bounds__(256) void k_sort(const int* __restrict__ gcnt,
                                              const uint2* __restrict__ pay,
                                              uint2* __restrict__ pay2,
                                              int* __restrict__ rstart) {
    __shared__ int cnt[RPB];
    __shared__ int ofs2[RPB];
    __shared__ int red[256];
    __shared__ uint2 stg[SCAP];   // 28 KB
    int b = blockIdx.x;
    int t = threadIdx.x;
    // s0 = sum_{i<b} gcnt[i]
    int part = 0;
    for (int i = t; i < b; i += 256) part += gcnt[i];
    red[t] = part;
    __syncthreads();
    for (int off = 128; off > 0; off >>= 1) {
        if (t < off) red[t] += red[t + off];
        __syncthreads();
    }
    int s0 = red[0];
    int n = gcnt[b];
    if (t < RPB) cnt[t] = 0;
    __syncthreads();
    for (int i = t; i < n; i += 256)
        atomicAdd(&cnt[pay[s0 + i].x & 63], 1);
    __syncthreads();
    if (t < RPB) {
        int v = cnt[t];
        int s = v;
        for (int off = 1; off < 64; off <<= 1) {
            int u = __shfl_up(s, off, 64);
            if (t >= off) s += u;
        }
        int ex = s - v;               // exclusive
        ofs2[t] = ex;
        int r0 = b * RPB;
        int nrows = NN - r0; if (nrows > RPB) nrows = RPB;
        if (t < nrows) rstart[r0 + t] = s0 + ex;
    }
    __syncthreads();
    for (int i = t; i < n; i += 256) {
        uint2 p = pay[s0 + i];
        int rl = p.x & 63;
        int pos = atomicAdd(&ofs2[rl], 1);
        stg[pos] = make_uint2((p.x >> 6) & 0xFFFF, p.y);
    }
    __syncthreads();
    for (int i = t; i < n; i += 256)
        pay2[s0 + i] = stg[i];
}

// ---- row-parallel softmax stats: one wave per row -> K = m + log(s+eps);
//      also emits self-loop alpha + self idx echo ----
__global__ __launch_bounds__(256) void k_row(const int* __restrict__ rstart,
                                             const uint2* __restrict__ pay2,
                                             float* __restrict__ yk,
                                             const float* __restrict__ y2,
                                             float* __restrict__ alpha,
                                             float* __restrict__ oidx) {
    int wv = threadIdx.x >> 6;
    int lane = threadIdx.x & 63;
    int r = blockIdx.x * 4 + wv;
    if (r >= NN) return;
    int sub = lane >> 3;   // edge slot within chunk (0..7)
    int h = lane & 7;      // head
    int s0 = rstart[r];
    int deg = rstart[r + 1] - s0;
    int tot = deg + 1;     // + self loop at slot == deg
    float yh = yk[(size_t)r * 16 + h];
    float y2s = y2[(size_t)r * 8 + h];
    float cache[NIT];
    float mx = -__builtin_inff();
#pragma unroll
    for (int it = 0; it < NIT; ++it) {
        int i = it * 8 + sub;
        float a = -__builtin_inff();
        if (i < deg) {
            uint2 p = pay2[s0 + i];
            a = act((yh + y2[(size_t)p.x * 8 + h]) * __uint_as_float(p.y));
        } else if (i == deg) {
            a = act(yh + y2s);
        }
        cache[it] = a;
        mx = fmaxf(mx, a);
    }
    for (int i = NIT * 8 + sub; i < tot; i += 8) {
        float a;
        if (i < deg) {
            uint2 p = pay2[s0 + i];
            a = act((yh + y2[(size_t)p.x * 8 + h]) * __uint_as_float(p.y));
        } else {
            a = act(yh + y2s);
        }
        mx = fmaxf(mx, a);
    }
    mx = fmaxf(mx, __shfl_xor(mx, 8, 64));
    mx = fmaxf(mx, __shfl_xor(mx, 16, 64));
    mx = fmaxf(mx, __shfl_xor(mx, 32, 64));
    float sum = 0.f;
#pragma unroll
    for (int it = 0; it < NIT; ++it)
        sum += __expf(cache[it] - mx);   // exp(-inf) = 0 for empty slots
    for (int i = NIT * 8 + sub; i < tot; i += 8) {
        float a;
        if (i < deg) {
            uint2 p = pay2[s0 + i];
            a = act((yh + y2[(size_t)p.x * 8 + h]) * __uint_as_float(p.y));
        } else {
            a = act(yh + y2s);
        }
        sum += __expf(a - mx);
    }
    sum += __shfl_xor(sum, 8, 64);
    sum += __shfl_xor(sum, 16, 64);
    sum += __shfl_xor(sum, 32, 64);
    if (sub == 0) {
        float K = mx + __logf(sum + 1e-16f);
        yk[(size_t)r * 16 + 8 + h] = K;
        // self-loop output row e = EE + r
        float os = __expf(act(yh + y2s) - K);
        __builtin_nontemporal_store(os, &alpha[(size_t)(EE + r) * 8 + h]);
        if (h == 0) __builtin_nontemporal_store((float)r, &oidx[EE + r]);
        if (h == 1) __builtin_nontemporal_store((float)r, &oidx[(size_t)TOT + EE + r]);
    }
}

// ---- finalize (e < EE only): grid-stride, 2-edge software pipeline ----
__global__ __launch_bounds__(256) void k_final(const int* __restrict__ rowp,
                                               const int* __restrict__ colp,
                                               const float* __restrict__ ea,
                                               const float* __restrict__ yk,
                                               const float* __restrict__ y2,
                                               float* __restrict__ alpha,
                                               float* __restrict__ oidx) {
    int gid = blockIdx.x * 256 + threadIdx.x;
    int h = gid & 7;
    int g0 = gid >> 3;
    const int stride = (GRIDF * 256) >> 3;   // edges per step
    for (int e = g0; e < EE; e += 2 * stride) {
        int e1 = e + stride;
        bool has1 = e1 < EE;
        int r0 = __builtin_nontemporal_load(&rowp[e]);
        int c0 = __builtin_nontemporal_load(&colp[e]);
        float w0 = fabsf(__builtin_nontemporal_load(&ea[e]));
        int r1 = 0, c1 = 0; float w1 = 0.f;
        if (has1) {
            r1 = __builtin_nontemporal_load(&rowp[e1]);
            c1 = __builtin_nontemporal_load(&colp[e1]);
            w1 = fabsf(__builtin_nontemporal_load(&ea[e1]));
        }
        // issue all gathers (6 independent requests)
        float yv0 = yk[(size_t)r0 * 16 + h];
        float Kv0 = yk[(size_t)r0 * 16 + 8 + h];
        float vb0 = y2[(size_t)c0 * 8 + h];
        float yv1 = 0.f, Kv1 = 0.f, vb1 = 0.f;
        if (has1) {
            yv1 = yk[(size_t)r1 * 16 + h];
            Kv1 = yk[(size_t)r1 * 16 + 8 + h];
            vb1 = y2[(size_t)c1 * 8 + h];
        }
        float o0 = __expf(act((yv0 + vb0) * w0) - Kv0);
        __builtin_nontemporal_store(o0, &alpha[(size_t)e * 8 + h]);
        if (h == 0) __builtin_nontemporal_store((float)r0, &oidx[e]);
        if (h == 1) __builtin_nontemporal_store((float)c0, &oidx[(size_t)TOT + e]);
        if (has1) {
            float o1 = __expf(act((yv1 + vb1) * w1) - Kv1);
            __builtin_nontemporal_store(o1, &alpha[(size_t)e1 * 8 + h]);
            if (h == 0) __builtin_nontemporal_store((float)r1, &oidx[e1]);
            if (h == 1) __builtin_nontemporal_store((float)c1, &oidx[(size_t)TOT + e1]);
        }
    }
}

extern "C" void kernel_launch(void* const* d_in, const int* in_sizes, int n_in,
                              void* d_out, int out_size, void* d_ws, size_t ws_size,
                              hipStream_t stream) {
    const float* x    = (const float*)d_in[0];
    const int*   rowp = (const int*)d_in[1];          // edge_index[0]
    const int*   colp = rowp + EE;                    // edge_index[1]
    const float* ea   = (const float*)d_in[2];
    const float* W    = (const float*)d_in[3];
    const float* bias = (const float*)d_in[4];

    float* out_alpha = (float*)d_out;                 // [TOT][8]
    float* out_idx   = out_alpha + (size_t)TOT * 8;   // [2][TOT] as float

    // pay2 (row-sorted payload, EE uint2 = 12.8MB) lives in the out_alpha
    // region (bytes 0..12.8MB); self-loop alphas start at byte 51.2MB.
    uint2* pay2 = (uint2*)out_alpha;

    // workspace layout
    float*  yk     = (float*)d_ws;                    // NN*16 (y1b | K), 64B/row
    float*  y2     = yk + (size_t)NN * 16;            // NN*8
    uint2*  pay    = (uint2*)(y2 + (size_t)NN * 8);   // EE uint2 (12.8 MB)
    int*    gcnt   = (int*)(pay + (size_t)EE);        // NB
    int*    gcur0  = gcnt + NB;                       // NB (zeroed by k_proj)
    int*    rstart = gcur0 + NB;                      // NN+1

    k_proj<<<(NN * 16 + 255) / 256, 256, 0, stream>>>(x, W, bias, yk, y2,
                                                      gcnt, gcur0, rstart);
    k_hist<<<NBB, 1024, 0, stream>>>(rowp, gcnt);
    k_bin<<<NBB, 1024, 0, stream>>>(rowp, colp, ea, gcnt, gcur0, pay);
    k_sort<<<NB, 256, 0, stream>>>(gcnt, pay, pay2, rstart);
    k_row<<<(NN + 3) / 4, 256, 0, stream>>>(rstart, pay2, yk, y2,
                                            out_alpha, out_idx);
    k_final<<<GRIDF, 256, 0, stream>>>(rowp, colp, ea, yk, y2,
                                       out_alpha, out_idx);
}

// Round 12
// 111.449 us; speedup vs baseline: 1.3328x; 1.2584x over previous
//
#include <hip/hip_runtime.h>

#define NN 50000
#define EE 1600000
#define CC 128
#define HH 8
#define TOT (EE + NN)               // 1,650,000 output rows
#define RPB 64                      // rows per bucket
#define NB  ((NN + RPB - 1) / RPB)  // 782 buckets
#define BCH 4096                    // edges per binning block
#define NBB ((EE + BCH - 1) / BCH)  // 391 binning blocks
#define SCAP 3584                   // sort stage capacity (mean 2048)
#define NIT 8                       // cached iterations (tot<=64 typical)
#define GRIDF 4096                  // k_final grid-stride blocks
#define SRT 512                     // k_sortrow block size (8 waves)

typedef unsigned long long ull;

// leaky_relu(z,0.2)*100
__device__ inline float act(float z) {
    z = (z >= 0.f) ? z : 0.2f * z;
    return z * 100.f;
}

// ---- yk[r] = [x@W1 + b (8) | K placeholder (8)], y2 = x @ W[C:] ----
// block 0 additionally zero-inits gcnt/gcur0
__global__ __launch_bounds__(256) void k_proj(const float* __restrict__ x,
                                              const float* __restrict__ W,
                                              const float* __restrict__ bias,
                                              float* __restrict__ yk,
                                              float* __restrict__ y2,
                                              int* __restrict__ gcnt,
                                              int* __restrict__ gcur0) {
    if (blockIdx.x == 0) {
        for (int i = threadIdx.x; i < NB; i += 256) { gcnt[i] = 0; gcur0[i] = 0; }
    }
    __shared__ float w[2 * CC * HH];  // 2048 floats
    int tid = threadIdx.x;
    for (int i = tid; i < 2 * CC * HH; i += 256) w[i] = W[i];
    __syncthreads();
    int node = blockIdx.x * 16 + (tid >> 4);
    int j = tid & 15;
    if (node >= NN) return;
    int wofs = (j < 8) ? j : (CC * HH + j - 8);
    const float4* xv = (const float4*)(x + (size_t)node * CC);
    float acc = 0.f;
#pragma unroll 4
    for (int k4 = 0; k4 < CC / 4; ++k4) {
        float4 xx = xv[k4];
        int base = k4 * 32 + wofs;
        acc += xx.x * w[base];
        acc += xx.y * w[base + 8];
        acc += xx.z * w[base + 16];
        acc += xx.w * w[base + 24];
    }
    if (j < 8) yk[(size_t)node * 16 + j] = acc + bias[j];
    else       y2[(size_t)node * 8 + (j - 8)] = acc;
}

// ---- bucket histogram: LDS-aggregated ----
__global__ __launch_bounds__(1024) void k_hist(const int* __restrict__ rowp,
                                               int* __restrict__ gcnt) {
    __shared__ int h[NB];
    int t = threadIdx.x;
    for (int i = t; i < NB; i += 1024) h[i] = 0;
    __syncthreads();
    int base = blockIdx.x * BCH;
    int n = EE - base; if (n > BCH) n = BCH;
    for (int i = t; i < n; i += 1024)
        atomicAdd(&h[rowp[base + i] >> 6], 1);
    __syncthreads();
    for (int i = t; i < NB; i += 1024)
        if (h[i]) atomicAdd(&gcnt[i], h[i]);
}

// ---- binning: fused global+local scan (packed u64); LDS stage; coalesced flush
__global__ __launch_bounds__(1024) void k_bin(const int* __restrict__ rowp,
                                              const int* __restrict__ colp,
                                              const float* __restrict__ ea,
                                              const int* __restrict__ gcnt,
                                              int* __restrict__ gcur0,
                                              uint2* __restrict__ pay) {
    __shared__ int hist[NB];
    __shared__ int lscan[NB];
    __shared__ int lofs[NB];
    __shared__ int gofs[NB];
    __shared__ ull sc[1024];
    __shared__ uint2 stage[BCH];   // 32 KB
    int t = threadIdx.x;
    int base = blockIdx.x * BCH;
    int n = EE - base; if (n > BCH) n = BCH;
    for (int i = t; i < NB; i += 1024) hist[i] = 0;
    __syncthreads();
    for (int i = t; i < n; i += 1024)
        atomicAdd(&hist[rowp[base + i] >> 6], 1);
    __syncthreads();
    // packed scan: high 32 = global gcnt, low 32 = local hist
    int og  = (t < NB) ? gcnt[t] : 0;
    int own = (t < NB) ? hist[t] : 0;
    sc[t] = ((ull)(unsigned)og << 32) | (unsigned)own;
    __syncthreads();
    for (int off = 1; off < 1024; off <<= 1) {
        ull v = (t >= off) ? sc[t - off] : 0ull;
        __syncthreads();
        sc[t] += v;
        __syncthreads();
    }
    if (t < NB) {
        int gb = (int)(sc[t] >> 32) - og;             // global bucket base
        int ex = (int)(sc[t] & 0xFFFFFFFFu) - own;    // local stage base
        lscan[t] = ex;
        lofs[t] = ex;
        gofs[t] = own ? (gb + atomicAdd(&gcur0[t], own)) : 0;
    }
    __syncthreads();
    // place packed payload into stage, grouped by bucket
    for (int i = t; i < n; i += 1024) {
        int r = rowp[base + i];
        int c = colp[base + i];
        float w = fabsf(ea[base + i]);
        int bkt = r >> 6;
        int p = atomicAdd(&lofs[bkt], 1);
        stage[p] = make_uint2((unsigned)(r & 63) | ((unsigned)c << 6) |
                              ((unsigned)bkt << 22),
                              __float_as_uint(w));
    }
    __syncthreads();
    // flush: consecutive staged slots of a bucket -> consecutive global slots
    for (int i = t; i < n; i += 1024) {
        uint2 v = stage[i];
        int bkt = v.x >> 22;
        pay[gofs[bkt] + (i - lscan[bkt])] = v;
    }
}

// ---- fused: per-bucket counting sort (LDS) + per-row wave softmax stats ----
// writes K into yk, and the self-loop output rows
__global__ __launch_bounds__(SRT) void k_sortrow(const int* __restrict__ gcnt,
                                                 const uint2* __restrict__ pay,
                                                 float* __restrict__ yk,
                                                 const float* __restrict__ y2,
                                                 float* __restrict__ alpha,
                                                 float* __restrict__ oidx) {
    __shared__ int cnt[RPB];
    __shared__ int rstartL[RPB + 1];
    __shared__ int ofs2[RPB];
    __shared__ int red[SRT];
    __shared__ uint2 stg[SCAP];   // 28 KB
    int b = blockIdx.x;
    int t = threadIdx.x;
    // s0 = sum_{i<b} gcnt[i]
    int part = 0;
    for (int i = t; i < b; i += SRT) part += gcnt[i];
    red[t] = part;
    __syncthreads();
    for (int off = SRT / 2; off > 0; off >>= 1) {
        if (t < off) red[t] += red[t + off];
        __syncthreads();
    }
    int s0 = red[0];
    int n = gcnt[b];
    if (t < RPB) cnt[t] = 0;
    __syncthreads();
    for (int i = t; i < n; i += SRT)
        atomicAdd(&cnt[pay[s0 + i].x & 63], 1);
    __syncthreads();
    if (t < RPB) {
        int v = cnt[t];
        int s = v;
        for (int off = 1; off < 64; off <<= 1) {
            int u = __shfl_up(s, off, 64);
            if (t >= off) s += u;
        }
        int ex = s - v;               // exclusive
        ofs2[t] = ex;
        rstartL[t] = ex;
        if (t == RPB - 1) rstartL[RPB] = s;   // == n
    }
    __syncthreads();
    for (int i = t; i < n; i += SRT) {
        uint2 p = pay[s0 + i];
        int rl = p.x & 63;
        int pos = atomicAdd(&ofs2[rl], 1);
        stg[pos] = make_uint2((p.x >> 6) & 0xFFFF, p.y);
    }
    __syncthreads();
    // row phase: 8 waves x 8 rows each, edges read from LDS
    int wv = t >> 6;
    int lane = t & 63;
    int sub = lane >> 3;   // edge slot within chunk (0..7)
    int h = lane & 7;      // head
    int r0 = b * RPB;
    for (int q = 0; q < 8; ++q) {
        int rr = wv * 8 + q;
        int r = r0 + rr;
        if (r >= NN) break;
        int ls = rstartL[rr];
        int ldeg = rstartL[rr + 1] - ls;
        int tot = ldeg + 1;     // + self loop at slot == ldeg
        float yh = yk[(size_t)r * 16 + h];
        float y2s = y2[(size_t)r * 8 + h];
        float cache[NIT];
        float mx = -__builtin_inff();
#pragma unroll
        for (int it = 0; it < NIT; ++it) {
            int i = it * 8 + sub;
            float a = -__builtin_inff();
            if (i < ldeg) {
                uint2 p = stg[ls + i];
                a = act((yh + y2[(size_t)p.x * 8 + h]) * __uint_as_float(p.y));
            } else if (i == ldeg) {
                a = act(yh + y2s);
            }
            cache[it] = a;
            mx = fmaxf(mx, a);
        }
        for (int i = NIT * 8 + sub; i < tot; i += 8) {
            float a;
            if (i < ldeg) {
                uint2 p = stg[ls + i];
                a = act((yh + y2[(size_t)p.x * 8 + h]) * __uint_as_float(p.y));
            } else {
                a = act(yh + y2s);
            }
            mx = fmaxf(mx, a);
        }
        mx = fmaxf(mx, __shfl_xor(mx, 8, 64));
        mx = fmaxf(mx, __shfl_xor(mx, 16, 64));
        mx = fmaxf(mx, __shfl_xor(mx, 32, 64));
        float sum = 0.f;
#pragma unroll
        for (int it = 0; it < NIT; ++it)
            sum += __expf(cache[it] - mx);   // exp(-inf)=0 for empty slots
        for (int i = NIT * 8 + sub; i < tot; i += 8) {
            float a;
            if (i < ldeg) {
                uint2 p = stg[ls + i];
                a = act((yh + y2[(size_t)p.x * 8 + h]) * __uint_as_float(p.y));
            } else {
                a = act(yh + y2s);
            }
            sum += __expf(a - mx);
        }
        sum += __shfl_xor(sum, 8, 64);
        sum += __shfl_xor(sum, 16, 64);
        sum += __shfl_xor(sum, 32, 64);
        if (sub == 0) {
            float K = mx + __logf(sum + 1e-16f);
            yk[(size_t)r * 16 + 8 + h] = K;
            // self-loop output row e = EE + r
            float os = __expf(act(yh + y2s) - K);
            __builtin_nontemporal_store(os, &alpha[(size_t)(EE + r) * 8 + h]);
            if (h == 0) __builtin_nontemporal_store((float)r, &oidx[EE + r]);
            if (h == 1)
                __builtin_nontemporal_store((float)r, &oidx[(size_t)TOT + EE + r]);
        }
    }
}

// ---- finalize (e < EE only): grid-stride, 4-edge software pipeline ----
__global__ __launch_bounds__(256) void k_final(const int* __restrict__ rowp,
                                               const int* __restrict__ colp,
                                               const float* __restrict__ ea,
                                               const float* __restrict__ yk,
                                               const float* __restrict__ y2,
                                               float* __restrict__ alpha,
                                               float* __restrict__ oidx) {
    int gid = blockIdx.x * 256 + threadIdx.x;
    int h = gid & 7;
    int g0 = gid >> 3;
    const int stride = (GRIDF * 256) >> 3;   // edges per step
    for (int e0 = g0; e0 < EE; e0 += 4 * stride) {
        int rr[4], cc[4]; float ww[4]; bool hv[4];
#pragma unroll
        for (int u = 0; u < 4; ++u) {
            int e = e0 + u * stride;
            hv[u] = e < EE;
            rr[u] = 0; cc[u] = 0; ww[u] = 0.f;
            if (hv[u]) {
                rr[u] = rowp[e];
                cc[u] = colp[e];
                ww[u] = fabsf(ea[e]);
            }
        }
        float yv[4], Kv[4], vb[4];
#pragma unroll
        for (int u = 0; u < 4; ++u) {
            yv[u] = 0.f; Kv[u] = 0.f; vb[u] = 0.f;
            if (hv[u]) {
                yv[u] = yk[(size_t)rr[u] * 16 + h];
                Kv[u] = yk[(size_t)rr[u] * 16 + 8 + h];
                vb[u] = y2[(size_t)cc[u] * 8 + h];
            }
        }
#pragma unroll
        for (int u = 0; u < 4; ++u) {
            if (hv[u]) {
                int e = e0 + u * stride;
                float o = __expf(act((yv[u] + vb[u]) * ww[u]) - Kv[u]);
                __builtin_nontemporal_store(o, &alpha[(size_t)e * 8 + h]);
                if (h == 0) __builtin_nontemporal_store((float)rr[u], &oidx[e]);
                if (h == 1)
                    __builtin_nontemporal_store((float)cc[u], &oidx[(size_t)TOT + e]);
            }
        }
    }
}

extern "C" void kernel_launch(void* const* d_in, const int* in_sizes, int n_in,
                              void* d_out, int out_size, void* d_ws, size_t ws_size,
                              hipStream_t stream) {
    const float* x    = (const float*)d_in[0];
    const int*   rowp = (const int*)d_in[1];          // edge_index[0]
    const int*   colp = rowp + EE;                    // edge_index[1]
    const float* ea   = (const float*)d_in[2];
    const float* W    = (const float*)d_in[3];
    const float* bias = (const float*)d_in[4];

    float* out_alpha = (float*)d_out;                 // [TOT][8]
    float* out_idx   = out_alpha + (size_t)TOT * 8;   // [2][TOT] as float

    // workspace layout
    float*  yk     = (float*)d_ws;                    // NN*16 (y1b | K), 64B/row
    float*  y2     = yk + (size_t)NN * 16;            // NN*8
    uint2*  pay    = (uint2*)(y2 + (size_t)NN * 8);   // EE uint2 (12.8 MB)
    int*    gcnt   = (int*)(pay + (size_t)EE);        // NB
    int*    gcur0  = gcnt + NB;                       // NB (zeroed by k_proj)

    k_proj<<<(NN * 16 + 255) / 256, 256, 0, stream>>>(x, W, bias, yk, y2,
                                                      gcnt, gcur0);
    k_hist<<<NBB, 1024, 0, stream>>>(rowp, gcnt);
    k_bin<<<NBB, 1024, 0, stream>>>(rowp, colp, ea, gcnt, gcur0, pay);
    k_sortrow<<<NB, SRT, 0, stream>>>(gcnt, pay, yk, y2, out_alpha, out_idx);
    k_final<<<GRIDF, 256, 0, stream>>>(rowp, colp, ea, yk, y2,
                                       out_alpha, out_idx);
}

// Round 13
// 98.370 us; speedup vs baseline: 1.5099x; 1.1330x over previous
//
#include <hip/hip_runtime.h>

#define NN 50000
#define EE 1600000
#define CC 128
#define HH 8
#define TOT (EE + NN)               // 1,650,000 output rows
#define RPB 64                      // rows per bucket
#define NB  ((NN + RPB - 1) / RPB)  // 782 buckets
#define CAP 2560                    // fixed slots per bucket (mean 2048, +11 sigma)
#define BCH 4096                    // edges per binning block
#define NBB ((EE + BCH - 1) / BCH)  // 391 binning blocks
#define NIT 8                       // cached iterations (tot<=64 typical)
#define GRIDF 4096                  // k_final grid-stride blocks
#define SRT 512                     // k_sortrow block size (8 waves)

typedef unsigned long long ull;

// leaky_relu(z,0.2)*100
__device__ inline float act(float z) {
    z = (z >= 0.f) ? z : 0.2f * z;
    return z * 100.f;
}

// ---- yk[r] = [x@W1 + b (8) | K placeholder (8)], y2 = x @ W[C:] ----
// block 0 additionally zero-inits gcur0
__global__ __launch_bounds__(256) void k_proj(const float* __restrict__ x,
                                              const float* __restrict__ W,
                                              const float* __restrict__ bias,
                                              float* __restrict__ yk,
                                              float* __restrict__ y2,
                                              int* __restrict__ gcur0) {
    if (blockIdx.x == 0) {
        for (int i = threadIdx.x; i < NB; i += 256) gcur0[i] = 0;
    }
    __shared__ float w[2 * CC * HH];  // 2048 floats
    int tid = threadIdx.x;
    for (int i = tid; i < 2 * CC * HH; i += 256) w[i] = W[i];
    __syncthreads();
    int node = blockIdx.x * 16 + (tid >> 4);
    int j = tid & 15;
    if (node >= NN) return;
    int wofs = (j < 8) ? j : (CC * HH + j - 8);
    const float4* xv = (const float4*)(x + (size_t)node * CC);
    float acc = 0.f;
#pragma unroll 4
    for (int k4 = 0; k4 < CC / 4; ++k4) {
        float4 xx = xv[k4];
        int base = k4 * 32 + wofs;
        acc += xx.x * w[base];
        acc += xx.y * w[base + 8];
        acc += xx.z * w[base + 16];
        acc += xx.w * w[base + 24];
    }
    if (j < 8) yk[(size_t)node * 16 + j] = acc + bias[j];
    else       y2[(size_t)node * 8 + (j - 8)] = acc;
}

// ---- binning into fixed-capacity bucket regions; LDS stage; coalesced flush
__global__ __launch_bounds__(1024) void k_bin(const int* __restrict__ rowp,
                                              const int* __restrict__ colp,
                                              const float* __restrict__ ea,
                                              int* __restrict__ gcur0,
                                              uint2* __restrict__ pay) {
    __shared__ int hist[NB];
    __shared__ int lscan[NB];
    __shared__ int lofs[NB];
    __shared__ int gofs[NB];
    __shared__ int sc[1024];
    __shared__ uint2 stage[BCH];   // 32 KB
    int t = threadIdx.x;
    int base = blockIdx.x * BCH;
    int n = EE - base; if (n > BCH) n = BCH;
    for (int i = t; i < NB; i += 1024) hist[i] = 0;
    __syncthreads();
    for (int i = t; i < n; i += 1024)
        atomicAdd(&hist[rowp[base + i] >> 6], 1);
    __syncthreads();
    // local scan for stage layout
    int own = (t < NB) ? hist[t] : 0;
    sc[t] = own;
    __syncthreads();
    for (int off = 1; off < 1024; off <<= 1) {
        int v = (t >= off) ? sc[t - off] : 0;
        __syncthreads();
        sc[t] += v;
        __syncthreads();
    }
    if (t < NB) {
        int ex = sc[t] - own;
        lscan[t] = ex;
        lofs[t] = ex;
        gofs[t] = own ? (t * CAP + atomicAdd(&gcur0[t], own)) : 0;
    }
    __syncthreads();
    // place packed payload into stage, grouped by bucket
    for (int i = t; i < n; i += 1024) {
        int r = rowp[base + i];
        int c = colp[base + i];
        float w = fabsf(ea[base + i]);
        int bkt = r >> 6;
        int p = atomicAdd(&lofs[bkt], 1);
        stage[p] = make_uint2((unsigned)(r & 63) | ((unsigned)c << 6) |
                              ((unsigned)bkt << 22),
                              __float_as_uint(w));
    }
    __syncthreads();
    // flush: consecutive staged slots of a bucket -> consecutive global slots
    for (int i = t; i < n; i += 1024) {
        uint2 v = stage[i];
        int bkt = v.x >> 22;
        int idx = gofs[bkt] + (i - lscan[bkt]);
        if (idx < (bkt + 1) * CAP)          // overflow guard (p ~ 1e-26)
            pay[idx] = v;
    }
}

// ---- fused: per-bucket counting sort (LDS) + per-row wave softmax stats ----
// writes K into yk, and the self-loop output rows
__global__ __launch_bounds__(SRT) void k_sortrow(const int* __restrict__ gcur0,
                                                 const uint2* __restrict__ pay,
                                                 float* __restrict__ yk,
                                                 const float* __restrict__ y2,
                                                 float* __restrict__ alpha,
                                                 float* __restrict__ oidx) {
    __shared__ int cnt[RPB];
    __shared__ int rstartL[RPB + 1];
    __shared__ int ofs2[RPB];
    __shared__ uint2 stg[CAP];   // 20.5 KB
    int b = blockIdx.x;
    int t = threadIdx.x;
    int s0 = b * CAP;
    int n = gcur0[b];
    if (n > CAP) n = CAP;
    if (t < RPB) cnt[t] = 0;
    __syncthreads();
    for (int i = t; i < n; i += SRT)
        atomicAdd(&cnt[pay[s0 + i].x & 63], 1);
    __syncthreads();
    if (t < RPB) {
        int v = cnt[t];
        int s = v;
        for (int off = 1; off < 64; off <<= 1) {
            int u = __shfl_up(s, off, 64);
            if (t >= off) s += u;
        }
        int ex = s - v;               // exclusive
        ofs2[t] = ex;
        rstartL[t] = ex;
        if (t == RPB - 1) rstartL[RPB] = s;   // == n
    }
    __syncthreads();
    for (int i = t; i < n; i += SRT) {
        uint2 p = pay[s0 + i];
        int rl = p.x & 63;
        int pos = atomicAdd(&ofs2[rl], 1);
        stg[pos] = make_uint2((p.x >> 6) & 0xFFFF, p.y);
    }
    __syncthreads();
    // row phase: 8 waves x 8 rows each, edges read from LDS
    int wv = t >> 6;
    int lane = t & 63;
    int sub = lane >> 3;   // edge slot within chunk (0..7)
    int h = lane & 7;      // head
    int r0 = b * RPB;
    for (int q = 0; q < 8; ++q) {
        int rr = wv * 8 + q;
        int r = r0 + rr;
        if (r >= NN) break;
        int ls = rstartL[rr];
        int ldeg = rstartL[rr + 1] - ls;
        int tot = ldeg + 1;     // + self loop at slot == ldeg
        float yh = yk[(size_t)r * 16 + h];
        float y2s = y2[(size_t)r * 8 + h];
        float cache[NIT];
        float mx = -__builtin_inff();
#pragma unroll
        for (int it = 0; it < NIT; ++it) {
            int i = it * 8 + sub;
            float a = -__builtin_inff();
            if (i < ldeg) {
                uint2 p = stg[ls + i];
                a = act((yh + y2[(size_t)p.x * 8 + h]) * __uint_as_float(p.y));
            } else if (i == ldeg) {
                a = act(yh + y2s);
            }
            cache[it] = a;
            mx = fmaxf(mx, a);
        }
        for (int i = NIT * 8 + sub; i < tot; i += 8) {
            float a;
            if (i < ldeg) {
                uint2 p = stg[ls + i];
                a = act((yh + y2[(size_t)p.x * 8 + h]) * __uint_as_float(p.y));
            } else {
                a = act(yh + y2s);
            }
            mx = fmaxf(mx, a);
        }
        mx = fmaxf(mx, __shfl_xor(mx, 8, 64));
        mx = fmaxf(mx, __shfl_xor(mx, 16, 64));
        mx = fmaxf(mx, __shfl_xor(mx, 32, 64));
        float sum = 0.f;
#pragma unroll
        for (int it = 0; it < NIT; ++it)
            sum += __expf(cache[it] - mx);   // exp(-inf)=0 for empty slots
        for (int i = NIT * 8 + sub; i < tot; i += 8) {
            float a;
            if (i < ldeg) {
                uint2 p = stg[ls + i];
                a = act((yh + y2[(size_t)p.x * 8 + h]) * __uint_as_float(p.y));
            } else {
                a = act(yh + y2s);
            }
            sum += __expf(a - mx);
        }
        sum += __shfl_xor(sum, 8, 64);
        sum += __shfl_xor(sum, 16, 64);
        sum += __shfl_xor(sum, 32, 64);
        if (sub == 0) {
            float K = mx + __logf(sum + 1e-16f);
            yk[(size_t)r * 16 + 8 + h] = K;
            // self-loop output row e = EE + r
            float os = __expf(act(yh + y2s) - K);
            __builtin_nontemporal_store(os, &alpha[(size_t)(EE + r) * 8 + h]);
            if (h == 0) __builtin_nontemporal_store((float)r, &oidx[EE + r]);
            if (h == 1)
                __builtin_nontemporal_store((float)r, &oidx[(size_t)TOT + EE + r]);
        }
    }
}

// ---- finalize (e < EE only): grid-stride, 4-edge software pipeline ----
__global__ __launch_bounds__(256) void k_final(const int* __restrict__ rowp,
                                               const int* __restrict__ colp,
                                               const float* __restrict__ ea,
                                               const float* __restrict__ yk,
                                               const float* __restrict__ y2,
                                               float* __restrict__ alpha,
                                               float* __restrict__ oidx) {
    int gid = blockIdx.x * 256 + threadIdx.x;
    int h = gid & 7;
    int g0 = gid >> 3;
    const int stride = (GRIDF * 256) >> 3;   // edges per step
    for (int e0 = g0; e0 < EE; e0 += 4 * stride) {
        int rr[4], cc[4]; float ww[4]; bool hv[4];
#pragma unroll
        for (int u = 0; u < 4; ++u) {
            int e = e0 + u * stride;
            hv[u] = e < EE;
            rr[u] = 0; cc[u] = 0; ww[u] = 0.f;
            if (hv[u]) {
                rr[u] = rowp[e];
                cc[u] = colp[e];
                ww[u] = fabsf(ea[e]);
            }
        }
        float yv[4], Kv[4], vb[4];
#pragma unroll
        for (int u = 0; u < 4; ++u) {
            yv[u] = 0.f; Kv[u] = 0.f; vb[u] = 0.f;
            if (hv[u]) {
                yv[u] = yk[(size_t)rr[u] * 16 + h];
                Kv[u] = yk[(size_t)rr[u] * 16 + 8 + h];
                vb[u] = y2[(size_t)cc[u] * 8 + h];
            }
        }
#pragma unroll
        for (int u = 0; u < 4; ++u) {
            if (hv[u]) {
                int e = e0 + u * stride;
                float o = __expf(act((yv[u] + vb[u]) * ww[u]) - Kv[u]);
                __builtin_nontemporal_store(o, &alpha[(size_t)e * 8 + h]);
                if (h == 0) __builtin_nontemporal_store((float)rr[u], &oidx[e]);
                if (h == 1)
                    __builtin_nontemporal_store((float)cc[u], &oidx[(size_t)TOT + e]);
            }
        }
    }
}

extern "C" void kernel_launch(void* const* d_in, const int* in_sizes, int n_in,
                              void* d_out, int out_size, void* d_ws, size_t ws_size,
                              hipStream_t stream) {
    const float* x    = (const float*)d_in[0];
    const int*   rowp = (const int*)d_in[1];          // edge_index[0]
    const int*   colp = rowp + EE;                    // edge_index[1]
    const float* ea   = (const float*)d_in[2];
    const float* W    = (const float*)d_in[3];
    const float* bias = (const float*)d_in[4];

    float* out_alpha = (float*)d_out;                 // [TOT][8]
    float* out_idx   = out_alpha + (size_t)TOT * 8;   // [2][TOT] as float

    // workspace layout
    float*  yk     = (float*)d_ws;                    // NN*16 (y1b | K), 64B/row
    float*  y2     = yk + (size_t)NN * 16;            // NN*8
    uint2*  pay    = (uint2*)(y2 + (size_t)NN * 8);   // NB*CAP uint2 (16.0 MB)
    int*    gcur0  = (int*)(pay + (size_t)NB * CAP);  // NB (zeroed by k_proj)

    k_proj<<<(NN * 16 + 255) / 256, 256, 0, stream>>>(x, W, bias, yk, y2, gcur0);
    k_bin<<<NBB, 1024, 0, stream>>>(rowp, colp, ea, gcur0, pay);
    k_sortrow<<<NB, SRT, 0, stream>>>(gcur0, pay, yk, y2, out_alpha, out_idx);
    k_final<<<GRIDF, 256, 0, stream>>>(rowp, colp, ea, yk, y2,
                                       out_alpha, out_idx);
}